// Round 8
// baseline (328.930 us; speedup 1.0000x reference)
//
#include <hip/hip_runtime.h>
#include <hip/hip_bf16.h>

#define S_LEN 2048
#define DMODEL 1024
#define NHEAD 16
#define DKEY 64
#define QSCALE 0.18033688011f  // 0.125 * log2(e): exp() -> exp2() domain

typedef __attribute__((ext_vector_type(8))) short bf16x8;
typedef __attribute__((ext_vector_type(4))) float f32x4;

__device__ __forceinline__ short f2bf(float f) {
  union { float f; unsigned u; } a; a.f = f;
  unsigned u = a.u;
  u += 0x7fff + ((u >> 16) & 1);   // RTNE
  return (short)(u >> 16);
}
__device__ __forceinline__ unsigned pk2bf(float a, float b) {
  union { __hip_bfloat162 h; unsigned u; } c;
  c.h = __float22bfloat162_rn(float2{a, b});
  return c.u;
}
__device__ __forceinline__ float fexp2(float x) {
#if __has_builtin(__builtin_amdgcn_exp2f)
  return __builtin_amdgcn_exp2f(x);
#else
  return exp2f(x);
#endif
}
__device__ __forceinline__ void gl_lds16(const void* g, void* l) {
  __builtin_amdgcn_global_load_lds(
      (const __attribute__((address_space(1))) unsigned int*)g,
      (__attribute__((address_space(3))) unsigned int*)l, 16, 0, 0);
}

// ---------------------------------------------------------------------------
// Kernel -1: X (q,k,v) fp32 -> bf16, elementwise. grid (4096, 3) x 256.
// ---------------------------------------------------------------------------
__global__ __launch_bounds__(256) void convert_x(
    const float* __restrict__ q, const float* __restrict__ k,
    const float* __restrict__ v, short* __restrict__ Xb) {
  const int z = blockIdx.y;
  const float* X = (z == 0) ? q : (z == 1) ? k : v;
  short* dst = Xb + (size_t)z * 4194304;
  const int i = (blockIdx.x * 256 + threadIdx.x) * 4;
  const float4 xv = *(const float4*)&X[i];
  uint2 o;
  o.x = pk2bf(xv.x, xv.y);
  o.y = pk2bf(xv.z, xv.w);
  *(uint2*)&dst[i] = o;
}

// ---------------------------------------------------------------------------
// Kernel 0: weight transpose+convert. W[k][n] f32 -> Wt[n][k] bf16, 4 weights.
// ---------------------------------------------------------------------------
__global__ __launch_bounds__(256) void convert_w(
    const float* __restrict__ Wq, const float* __restrict__ Wk,
    const float* __restrict__ Wv, const float* __restrict__ Wo,
    short* __restrict__ Wt) {
  __shared__ short T[64][72];
  const int z = blockIdx.z;
  const float* W = (z == 0) ? Wq : (z == 1) ? Wk : (z == 2) ? Wv : Wo;
  short* dst = Wt + (size_t)z * 1048576;
  const int k0 = blockIdx.x * 64, n0 = blockIdx.y * 64;
  const int t = threadIdx.x;
#pragma unroll
  for (int p = 0; p < 4; ++p) {
    const int r = p * 16 + (t >> 4), c = (t & 15) * 4;
    const float4 wv = *(const float4*)&W[(size_t)(k0 + r) * DMODEL + n0 + c];
    T[c + 0][r] = f2bf(wv.x);
    T[c + 1][r] = f2bf(wv.y);
    T[c + 2][r] = f2bf(wv.z);
    T[c + 3][r] = f2bf(wv.w);
  }
  __syncthreads();
  const int rr = t >> 2, cc = (t & 3) * 16;
  const bf16x8 x0 = *(const bf16x8*)&T[rr][cc];
  const bf16x8 x1 = *(const bf16x8*)&T[rr][cc + 8];
  short* d = dst + (size_t)(n0 + rr) * DMODEL + k0 + cc;
  *(bf16x8*)&d[0] = x0;
  *(bf16x8*)&d[8] = x1;
}

// ---------------------------------------------------------------------------
// BK=64 tile staging, conflict-free XOR swizzle over 8 chunks of 16 B.
// Tile [128][64] bf16 (128 B rows). Chunk g of row r at slot g^(r&7).
// Frag read slot = (kh*4+quad)^(l15&7): 2 lanes/bank -> free (m136).
// ---------------------------------------------------------------------------
__device__ __forceinline__ void stage_tile64(const short* gbase,
                                             short (*tile)[64], int w, int lane) {
  const int row = lane >> 3;                  // 0..7
  const int g = ((lane & 7) ^ row) * 8;       // de-swizzled global chunk
#pragma unroll
  for (int i = 0; i < 4; ++i) {
    const int r0 = w * 32 + i * 8;
    gl_lds16(gbase + (size_t)(r0 + row) * DMODEL + g, &tile[r0][0]);
  }
}

// ---------------------------------------------------------------------------
// Kernel 1: QKV projection, 128x128 tile, BK=64, all-bf16, swizzled LDS.
// z=0 Q (RoPE, scale=QSCALE -> [bh][s][dk]), z=1 K (RoPE), z=2 V^T.
// ---------------------------------------------------------------------------
__global__ __launch_bounds__(256) void gemm_qkv(
    const short* __restrict__ Xb, const short* __restrict__ Wt,
    const float* __restrict__ bq, const float* __restrict__ bk,
    const float* __restrict__ bv, const float* __restrict__ rope,
    short* __restrict__ Qw, short* __restrict__ Kw, short* __restrict__ Vw) {
  __shared__ char smem[36864];                     // 36 KB (epilogue reuse)
  short (*As)[64] = (short(*)[64])smem;            // 128x64 bf16, 16 KB
  short (*Bs)[64] = (short(*)[64])(smem + 16384);  // 128x64 bf16, 16 KB

  const int z = blockIdx.z;
  const short* X = Xb + (size_t)z * 4194304;
  const float* bias = (z == 0) ? bq : (z == 1) ? bk : bv;
  const short* Wz = Wt + (size_t)z * 1048576;

  const int m0 = blockIdx.x * 128, n0 = blockIdx.y * 128;
  const int t = threadIdx.x;
  const int lane = t & 63;
  const int w = t >> 6;
  const int quad = lane >> 4;
  const int l15 = lane & 15;
  const int wr = (w >> 1) * 64, wc = (w & 1) * 64;
  const int sw = l15 & 7;
  const int o0 = (quad ^ sw) * 8;          // k-half 0 chunk slot
  const int o1 = ((quad + 4) ^ sw) * 8;    // k-half 1 chunk slot

  f32x4 acc[4][4] = {};

  for (int kt = 0; kt < DMODEL; kt += 64) {
    __syncthreads();
    stage_tile64(X + (size_t)m0 * DMODEL + kt, As, w, lane);
    stage_tile64(Wz + (size_t)n0 * DMODEL + kt, Bs, w, lane);
    __syncthreads();
#pragma unroll
    for (int kh = 0; kh < 2; ++kh) {
      const int oo = kh ? o1 : o0;
      bf16x8 af[4], bf[4];
#pragma unroll
      for (int mi = 0; mi < 4; ++mi)
        af[mi] = *(const bf16x8*)&As[wr + mi * 16 + l15][oo];
#pragma unroll
      for (int nj = 0; nj < 4; ++nj)
        bf[nj] = *(const bf16x8*)&Bs[wc + nj * 16 + l15][oo];
#pragma unroll
      for (int mi = 0; mi < 4; ++mi)
#pragma unroll
        for (int nj = 0; nj < 4; ++nj)
          acc[mi][nj] = __builtin_amdgcn_mfma_f32_16x16x32_bf16(
              af[mi], bf[nj], acc[mi][nj], 0, 0, 0);
    }
  }

  const int b = (m0 + wr) >> 11;
  const int sbase = (m0 + wr) & 2047;

  if (z == 2) {
    __syncthreads();
    short (*tr)[72] = (short(*)[72])(smem + w * 9216);
    const int h = (n0 + wc) >> 6;
#pragma unroll
    for (int nj = 0; nj < 4; ++nj) {
      const float bval = bias[n0 + wc + nj * 16 + l15];
#pragma unroll
      for (int ti = 0; ti < 4; ++ti)
#pragma unroll
        for (int r = 0; r < 4; ++r)
          tr[nj * 16 + l15][ti * 16 + quad * 4 + r] = f2bf(acc[ti][nj][r] + bval);
    }
    asm volatile("s_waitcnt lgkmcnt(0)" ::: "memory");
    const int bh = b * NHEAD + h;
#pragma unroll
    for (int cc = 0; cc < 4; ++cc) {
      const int row = cc * 16 + (lane >> 2);
      const int c0 = (lane & 3) * 16;
      const bf16x8 x0 = *(const bf16x8*)&tr[row][c0];
      const bf16x8 x1 = *(const bf16x8*)&tr[row][c0 + 8];
      short* d = Vw + ((size_t)bh * DKEY + row) * S_LEN + sbase + c0;
      *(bf16x8*)&d[0] = x0;
      *(bf16x8*)&d[8] = x1;
    }
    return;
  }

  short* outw = (z == 0) ? Qw : Kw;
#pragma unroll
  for (int nj = 0; nj < 4; ++nj) {
    const int n = n0 + wc + nj * 16 + l15;
    const float bval = bias[n];
    const int h = n >> 6, dk = n & 63;
    const int bh = b * NHEAD + h;
#pragma unroll
    for (int ti = 0; ti < 4; ++ti) {
#pragma unroll
      for (int r = 0; r < 4; ++r) {
        const int s = sbase + ti * 16 + quad * 4 + r;
        float val = acc[ti][nj][r] + bval;
        const float cosv = rope[((size_t)b * S_LEN + s) * DKEY + (dk | 1)];
        const float sinv = rope[((size_t)b * S_LEN + s) * DKEY + (dk & ~1)];
        const float partner = __shfl_xor(val, 1);
        val = (dk & 1) ? (val * cosv + partner * sinv)
                       : (val * cosv - partner * sinv);
        if (z == 0) val *= QSCALE;  // 1/sqrt(64) * log2(e)
        outw[((size_t)bh * S_LEN + s) * DKEY + dk] = f2bf(val);
      }
    }
  }
}

// ---------------------------------------------------------------------------
// Kernel 2: block-cooperative causal flash attention.
// grid (32, 32), 256 thr; block x -> Q-chunk 31-x (longest first).
// Off-diagonal iterations skip the causal test; two-pass softmax in exp2
// domain (log2e folded into Q): max-butterfly -> exp2(s-mn) -> sum-butterfly.
// Mask: fmaf(vm-1, 1e12, sv) -- (vm-1)*1e12 FIRST (exact 0 when vm==1);
// the R7 form fmaf(vm, 1e12, sv-1e12) absorbed sv at 1e12 ulp=131072 and
// zeroed every score (absmax 1.38 failure).
// ---------------------------------------------------------------------------
__global__ __launch_bounds__(256) void attn_kernel(
    const short* __restrict__ Qw, const short* __restrict__ Kw,
    const short* __restrict__ Vw, const float* __restrict__ v_mask,
    short* __restrict__ Ow) {
  __shared__ short Kt[2][64][64];
  __shared__ short Vt[2][64][64];
  __shared__ short Sb[4][16][72];

  const int t = threadIdx.x;
  const int w = t >> 6;
  const int lane = t & 63;
  const int quad = lane >> 4;
  const int l15 = lane & 15;
  const int x8 = l15 & 7;
  const int bh = blockIdx.y;
  const int b = bh >> 4;
  const int h = bh & 15;

  const short* Kbase = Kw + (size_t)bh * S_LEN * DKEY;
  const short* Vbase = Vw + (size_t)bh * DKEY * S_LEN;
  const float* vmb = v_mask + (size_t)b * S_LEN;

  const int sRow = lane >> 3;
  const int sCh = (lane & 7) ^ sRow;

  const int c = 31 - (int)blockIdx.x;   // longest blocks dispatch first
  const int qb = c * 64;
  const int qrow = qb + w * 16 + l15;
  const int niter = c + 1;

  const short* Qp = Qw + ((size_t)bh * S_LEN + qrow) * DKEY;
  const bf16x8 q_lo = *(const bf16x8*)(Qp + quad * 8);
  const bf16x8 q_hi = *(const bf16x8*)(Qp + 32 + quad * 8);

  float m_i = -1.0e30f, l_i = 0.f;
  f32x4 acc[4] = {};
  int cur = 0;

  // stage j=0 into buf 0
#pragma unroll
  for (int i = 0; i < 2; ++i) {
    const int kr = w * 16 + i * 8 + sRow;
    gl_lds16(Kbase + (size_t)kr * DKEY + sCh * 8, &Kt[0][w * 16 + i * 8][0]);
    gl_lds16(Vbase + (size_t)kr * S_LEN + sCh * 8, &Vt[0][w * 16 + i * 8][0]);
  }

  auto step = [&](int it, bool DIAG) {
    const int j0 = it << 6;
    __syncthreads();   // buf[cur] staged; prev iteration's reads done
    if (it + 1 < niter) {
      const int jn = j0 + 64;
#pragma unroll
      for (int i = 0; i < 2; ++i) {
        const int kr = w * 16 + i * 8 + sRow;
        gl_lds16(Kbase + (size_t)(jn + kr) * DKEY + sCh * 8,
                 &Kt[cur ^ 1][w * 16 + i * 8][0]);
        gl_lds16(Vbase + (size_t)kr * S_LEN + jn + sCh * 8,
                 &Vt[cur ^ 1][w * 16 + i * 8][0]);
      }
    }
    // S^T = K·Q^T
    f32x4 sv[4];
#pragma unroll
    for (int kt = 0; kt < 4; ++kt) {
      const bf16x8 ka0 = *(const bf16x8*)&Kt[cur][kt * 16 + l15][(quad ^ x8) * 8];
      const bf16x8 ka1 =
          *(const bf16x8*)&Kt[cur][kt * 16 + l15][((4 + quad) ^ x8) * 8];
      f32x4 s = {};
      s = __builtin_amdgcn_mfma_f32_16x16x32_bf16(ka0, q_lo, s, 0, 0, 0);
      s = __builtin_amdgcn_mfma_f32_16x16x32_bf16(ka1, q_hi, s, 0, 0, 0);
      sv[kt] = s;
    }
    // key-padding mask (+ causal only on the diagonal tile)
#pragma unroll
    for (int kt = 0; kt < 4; ++kt) {
      const float4 vm = *(const float4*)&vmb[j0 + kt * 16 + quad * 4];
#pragma unroll
      for (int r = 0; r < 4; ++r) {
        float xv = fmaf(vm[r] - 1.0f, 1.0e12f, sv[kt][r]);
        if (DIAG && (j0 + kt * 16 + quad * 4 + r > qrow)) xv = -1.0e12f;
        sv[kt][r] = xv;
      }
    }
    // two-pass softmax: max butterfly, exp2 direct, sum butterfly
    float mloc = -1.0e30f;
#pragma unroll
    for (int kt = 0; kt < 4; ++kt)
#pragma unroll
      for (int r = 0; r < 4; ++r) mloc = fmaxf(mloc, sv[kt][r]);
    mloc = fmaxf(mloc, __shfl_xor(mloc, 16));
    mloc = fmaxf(mloc, __shfl_xor(mloc, 32));
    const float mn = fmaxf(m_i, mloc);
    const float alpha = fexp2(m_i - mn);
    float p[4][4], sl = 0.f;
#pragma unroll
    for (int kt = 0; kt < 4; ++kt)
#pragma unroll
      for (int r = 0; r < 4; ++r) {
        p[kt][r] = fexp2(sv[kt][r] - mn);
        sl += p[kt][r];
      }
    sl += __shfl_xor(sl, 16);
    sl += __shfl_xor(sl, 32);
    l_i = l_i * alpha + sl;
    m_i = mn;
#pragma unroll
    for (int dt = 0; dt < 4; ++dt)
#pragma unroll
      for (int r = 0; r < 4; ++r) acc[dt][r] *= alpha;
    // P (final, no rescale) -> A-layout via per-wave LDS
#pragma unroll
    for (int kt = 0; kt < 4; ++kt) {
      uint2 pw;
      pw.x = pk2bf(p[kt][0], p[kt][1]);
      pw.y = pk2bf(p[kt][2], p[kt][3]);
      *(uint2*)&Sb[w][l15][kt * 16 + quad * 4] = pw;
    }
    asm volatile("s_waitcnt lgkmcnt(0)" ::: "memory");
    const bf16x8 pf0 = *(const bf16x8*)&Sb[w][l15][quad * 8];
    const bf16x8 pf1 = *(const bf16x8*)&Sb[w][l15][32 + quad * 8];
#pragma unroll
    for (int dt = 0; dt < 4; ++dt) {
      const bf16x8 va0 = *(const bf16x8*)&Vt[cur][dt * 16 + l15][(quad ^ x8) * 8];
      acc[dt] = __builtin_amdgcn_mfma_f32_16x16x32_bf16(va0, pf0, acc[dt], 0, 0, 0);
      const bf16x8 va1 =
          *(const bf16x8*)&Vt[cur][dt * 16 + l15][((4 + quad) ^ x8) * 8];
      acc[dt] = __builtin_amdgcn_mfma_f32_16x16x32_bf16(va1, pf1, acc[dt], 0, 0, 0);
    }
    cur ^= 1;
  };

  for (int it = 0; it < niter - 1; ++it) step(it, false);
  step(niter - 1, true);

  // epilogue: O^T/l -> transpose via Sb -> Ow[b][s][h*64+d]
#pragma unroll
  for (int dt = 0; dt < 4; ++dt) {
    const float inv = 1.0f / l_i;
    uint2 ov;
    ov.x = pk2bf(acc[dt][0] * inv, acc[dt][1] * inv);
    ov.y = pk2bf(acc[dt][2] * inv, acc[dt][3] * inv);
    *(uint2*)&Sb[w][l15][dt * 16 + quad * 4] = ov;
  }
  asm volatile("s_waitcnt lgkmcnt(0)" ::: "memory");
  const int qr2 = lane >> 2;
  const int d0 = (lane & 3) * 16;
  const bf16x8 o0 = *(const bf16x8*)&Sb[w][qr2][d0];
  const bf16x8 o1 = *(const bf16x8*)&Sb[w][qr2][d0 + 8];
  short* dst =
      Ow + ((size_t)(b * S_LEN + qb + w * 16 + qr2)) * DMODEL + h * DKEY + d0;
  *(bf16x8*)&dst[0] = o0;
  *(bf16x8*)&dst[8] = o1;
}

// ---------------------------------------------------------------------------
// Kernel 3: output projection, BK=64 swizzled bf16 tiles. fp32 out + bias.
// ---------------------------------------------------------------------------
__global__ __launch_bounds__(256) void gemm_out(
    const short* __restrict__ A, const short* __restrict__ Wz,
    const float* __restrict__ bias, float* __restrict__ out) {
  __shared__ char smem[32768];
  short (*As)[64] = (short(*)[64])smem;
  short (*Bs)[64] = (short(*)[64])(smem + 16384);

  const int m0 = blockIdx.x * 128, n0 = blockIdx.y * 128;
  const int t = threadIdx.x;
  const int lane = t & 63;
  const int w = t >> 6;
  const int quad = lane >> 4;
  const int l15 = lane & 15;
  const int wr = (w >> 1) * 64, wc = (w & 1) * 64;
  const int sw = l15 & 7;
  const int o0 = (quad ^ sw) * 8;
  const int o1 = ((quad + 4) ^ sw) * 8;

  f32x4 acc[4][4] = {};

  for (int kt = 0; kt < DMODEL; kt += 64) {
    __syncthreads();
    stage_tile64(A + (size_t)m0 * DMODEL + kt, As, w, lane);
    stage_tile64(Wz + (size_t)n0 * DMODEL + kt, Bs, w, lane);
    __syncthreads();
#pragma unroll
    for (int kh = 0; kh < 2; ++kh) {
      const int oo = kh ? o1 : o0;
      bf16x8 af[4], bf[4];
#pragma unroll
      for (int mi = 0; mi < 4; ++mi)
        af[mi] = *(const bf16x8*)&As[wr + mi * 16 + l15][oo];
#pragma unroll
      for (int nj = 0; nj < 4; ++nj)
        bf[nj] = *(const bf16x8*)&Bs[wc + nj * 16 + l15][oo];
#pragma unroll
      for (int mi = 0; mi < 4; ++mi)
#pragma unroll
        for (int nj = 0; nj < 4; ++nj)
          acc[mi][nj] = __builtin_amdgcn_mfma_f32_16x16x32_bf16(
              af[mi], bf[nj], acc[mi][nj], 0, 0, 0);
    }
  }
#pragma unroll
  for (int nj = 0; nj < 4; ++nj) {
    const int n = n0 + wc + nj * 16 + l15;
    const float bval = bias[n];
#pragma unroll
    for (int ti = 0; ti < 4; ++ti)
#pragma unroll
      for (int r = 0; r < 4; ++r) {
        const int m = m0 + wr + ti * 16 + quad * 4 + r;
        out[(size_t)m * DMODEL + n] = acc[ti][nj][r] + bval;
      }
  }
}

// ---------------------------------------------------------------------------
extern "C" void kernel_launch(void* const* d_in, const int* in_sizes, int n_in,
                              void* d_out, int out_size, void* d_ws,
                              size_t ws_size, hipStream_t stream) {
  const float* q      = (const float*)d_in[0];
  const float* k      = (const float*)d_in[1];
  const float* v      = (const float*)d_in[2];
  const float* rope   = (const float*)d_in[3];
  const float* v_mask = (const float*)d_in[5];
  const float* Wq = (const float*)d_in[6];
  const float* bq = (const float*)d_in[7];
  const float* Wk = (const float*)d_in[8];
  const float* bk = (const float*)d_in[9];
  const float* Wv = (const float*)d_in[10];
  const float* bv = (const float*)d_in[11];
  const float* Wo = (const float*)d_in[12];
  const float* bo = (const float*)d_in[13];
  float* out = (float*)d_out;

  short* ws = (short*)d_ws;
  short* Qw = ws;                  // [bh][s][dk] bf16, 8 MB
  short* Kw = ws + 4194304;        // [bh][s][dk] bf16, 8 MB
  short* Vw = ws + 8388608;        // [bh][dk][s] bf16, 8 MB
  short* Ow = ws + 12582912;       // [b][s][dmodel] bf16, 8 MB
  short* Wt = ws + 16777216;       // 4x [n][k] bf16, 8 MB
  short* Xb = ws + 20971520;       // 3x [m][k] bf16, 24 MB (total 64 MB)

  convert_x<<<dim3(4096, 3), 256, 0, stream>>>(q, k, v, Xb);
  convert_w<<<dim3(16, 16, 4), 256, 0, stream>>>(Wq, Wk, Wv, Wo, Wt);
  gemm_qkv<<<dim3(32, 8, 3), 256, 0, stream>>>(Xb, Wt, bq, bk, bv, rope,
                                               Qw, Kw, Vw);
  attn_kernel<<<dim3(32, 32), 256, 0, stream>>>(Qw, Kw, Vw, v_mask, Ow);
  gemm_out<<<dim3(32, 8), 256, 0, stream>>>(Ow, Wt + 3145728, bo, out);
}